// Round 2
// baseline (4771.640 us; speedup 1.0000x reference)
//
#include <hip/hip_runtime.h>
#include <stdint.h>

// ActuatorPolicyNet: x[2048,512] -> LSTM(H=1024) -> fc1 -> fc2 -> mean head.
// Phase A: gx GEMM. Phase B: persistent-resident LSTM, unit-per-wave mapping,
// register-pinned w_hh, sentinel-polled cross-CU h exchange, single barrier/step.
// Phase C: fc GEMMs + head.

#define T_SEQ 2048
#define H 1024
#define G4 4096
#define K_IN 512
#define SENT 0x7FC0DEADu  // NaN bit pattern; real h values are never NaN

__device__ __forceinline__ float sigmoidf_(float x) { return 1.0f / (1.0f + __expf(-x)); }
__device__ __forceinline__ float tanhf_(float x) { return 1.0f - 2.0f / (1.0f + __expf(2.0f * x)); }

// ---------------- init: h_hist[0] = h0, rows 1..2048 = sentinel ----------------
__global__ void init_k(const float* __restrict__ h0, float* __restrict__ h_hist) {
  int idx = blockIdx.x * blockDim.x + threadIdx.x;
  if (idx < H) {
    h_hist[idx] = h0[idx];
  } else if (idx < (T_SEQ + 1) * H) {
    ((unsigned*)h_hist)[idx] = SENT;
  }
}

// ---------------- generic fp32 GEMM: C = act(A[M,K] @ Bw[N,K]^T + b1 (+ b2)) ----------------
#define BM 64
#define BN 64
#define BK 32
#define LDT 68  // padded LDS stride

template <bool RELU, bool HASB2>
__global__ __launch_bounds__(256) void gemm_bias_k(
    const float* __restrict__ A, const float* __restrict__ Bw,
    const float* __restrict__ b1, const float* __restrict__ b2,
    float* __restrict__ C, int M, int N, int K) {
  __shared__ float As[BK][LDT];
  __shared__ float Bs[BK][LDT];
  const int tid = threadIdx.x;
  const int m0 = blockIdx.y * BM;
  const int n0 = blockIdx.x * BN;
  const int tx = tid & 15, ty = tid >> 4;  // 16x16 threads, 4x4 microtile
  const int srow = tid >> 2;               // 0..63 staging row
  const int skq = tid & 3;                 // 0..3  staging k-quarter

  float acc[4][4];
#pragma unroll
  for (int i = 0; i < 4; i++)
#pragma unroll
    for (int j = 0; j < 4; j++) acc[i][j] = 0.f;

  const float* Arow = A + (size_t)(m0 + srow) * K;
  const float* Brow = Bw + (size_t)(n0 + srow) * K;

  for (int k0 = 0; k0 < K; k0 += BK) {
    float4 a0 = *(const float4*)(Arow + k0 + skq * 8);
    float4 a1 = *(const float4*)(Arow + k0 + skq * 8 + 4);
    float4 c0_ = *(const float4*)(Brow + k0 + skq * 8);
    float4 c1_ = *(const float4*)(Brow + k0 + skq * 8 + 4);
    __syncthreads();  // previous tile fully consumed
    const int kb = skq * 8;
    As[kb + 0][srow] = a0.x; As[kb + 1][srow] = a0.y; As[kb + 2][srow] = a0.z; As[kb + 3][srow] = a0.w;
    As[kb + 4][srow] = a1.x; As[kb + 5][srow] = a1.y; As[kb + 6][srow] = a1.z; As[kb + 7][srow] = a1.w;
    Bs[kb + 0][srow] = c0_.x; Bs[kb + 1][srow] = c0_.y; Bs[kb + 2][srow] = c0_.z; Bs[kb + 3][srow] = c0_.w;
    Bs[kb + 4][srow] = c1_.x; Bs[kb + 5][srow] = c1_.y; Bs[kb + 6][srow] = c1_.z; Bs[kb + 7][srow] = c1_.w;
    __syncthreads();
#pragma unroll
    for (int kk = 0; kk < BK; kk++) {
      float av[4], bv[4];
      *(float4*)av = *(const float4*)&As[kk][ty * 4];
      *(float4*)bv = *(const float4*)&Bs[kk][tx * 4];
#pragma unroll
      for (int i = 0; i < 4; i++)
#pragma unroll
        for (int j = 0; j < 4; j++) acc[i][j] = fmaf(av[i], bv[j], acc[i][j]);
    }
  }

  float bb[4];
#pragma unroll
  for (int j = 0; j < 4; j++) {
    bb[j] = b1[n0 + tx * 4 + j];
    if (HASB2) bb[j] += b2[n0 + tx * 4 + j];
  }
#pragma unroll
  for (int i = 0; i < 4; i++) {
    float4 o;
    float* op = (float*)&o;
#pragma unroll
    for (int j = 0; j < 4; j++) {
      float v = acc[i][j] + bb[j];
      op[j] = RELU ? fmaxf(v, 0.f) : v;
    }
    *(float4*)&C[(size_t)(m0 + ty * 4 + i) * N + n0 + tx * 4] = o;
  }
}

// ---------------- persistent LSTM recurrence ----------------
// 256 wgs x 256 thr (4 waves). wg owns 4 hidden units; wave owns 1 unit.
// Lane = s*4 + g: g = gate (i,f,g,o), s = k-segment of 64. Each lane pins
// w_hh[g*1024+unit][s*64..+64) in 64 VGPRs (asm pin defeats remat).
// Per step: 64-bit sentinel poll per thread -> double-buffered LDS stage ->
// ONE barrier -> 64 FMA (4 accs) -> shfl_xor butterfly+gather -> per-lane
// activations -> lane0 stores h(t+1) with device-scope relaxed atomic.
#define NWG 256
#define NTHR 256
#define HPAD 68  // LDS: +4 pad per 64-word block breaks bank-quad collision

__global__ __launch_bounds__(NTHR) void lstm_k(
    const float* __restrict__ gx, const float* __restrict__ w_hh,
    const float* __restrict__ c0, float* __restrict__ h_hist,
    float* __restrict__ out) {
  unsigned* h_u = (unsigned*)h_hist;
  __shared__ float hbuf[2][16 * HPAD];
  const int tid = threadIdx.x;
  const int wg = blockIdx.x;
  const int wave = tid >> 6, lane = tid & 63;
  const int g = lane & 3;        // gate: 0=i 1=f 2=g 3=o
  const int s = lane >> 2;       // k-segment (0..15), 64 values each
  const int unit = wg * 4 + wave;
  const int grow = g * 1024 + unit;

  // preload weights into registers and PIN them (defeat load rematerialization)
  float wreg[64];
  {
    const float* wp = w_hh + (size_t)grow * H + s * 64;
#pragma unroll
    for (int j = 0; j < 64; j += 4) {
      float4 w4 = *(const float4*)(wp + j);
      wreg[j] = w4.x; wreg[j + 1] = w4.y; wreg[j + 2] = w4.z; wreg[j + 3] = w4.w;
    }
#pragma unroll
    for (int j = 0; j < 64; j++) asm volatile("" : "+v"(wreg[j]));
  }
  float c = c0[unit];  // redundant across the 16 g==0 lanes; garbage in others is unused

  const int stage_idx = 4 * tid + (tid >> 4) * 4;  // padded LDS index for words [4tid,4tid+4)
  for (int t = 0; t < T_SEQ; t++) {
    const int buf = t & 1;
    // prefetch this step's gx so its latency overlaps the poll
    float gxv = gx[(size_t)t * G4 + grow];
    asm volatile("" : "+v"(gxv));  // force issue before poll loop

    // stage h(t): two 64-bit sentinel polls per thread, then LDS
    {
      uint64_t* src = (uint64_t*)(h_u + (size_t)t * H) + tid * 2;
      uint64_t a = __hip_atomic_load(&src[0], __ATOMIC_RELAXED, __HIP_MEMORY_SCOPE_AGENT);
      uint64_t b = __hip_atomic_load(&src[1], __ATOMIC_RELAXED, __HIP_MEMORY_SCOPE_AGENT);
      while ((unsigned)a == SENT || (unsigned)(a >> 32) == SENT)
        a = __hip_atomic_load(&src[0], __ATOMIC_RELAXED, __HIP_MEMORY_SCOPE_AGENT);
      while ((unsigned)b == SENT || (unsigned)(b >> 32) == SENT)
        b = __hip_atomic_load(&src[1], __ATOMIC_RELAXED, __HIP_MEMORY_SCOPE_AGENT);
      float4 v;
      v.x = __uint_as_float((unsigned)a);
      v.y = __uint_as_float((unsigned)(a >> 32));
      v.z = __uint_as_float((unsigned)b);
      v.w = __uint_as_float((unsigned)(b >> 32));
      *(float4*)&hbuf[buf][stage_idx] = v;
    }
    __syncthreads();  // the only barrier per step (double-buffered hbuf)

    // 64 MACs with 4 accumulators (short dependency chains)
    float acc0 = 0.f, acc1 = 0.f, acc2 = 0.f, acc3 = 0.f;
    const float* hs = &hbuf[buf][s * HPAD];
#pragma unroll
    for (int j = 0; j < 16; j++) {
      float4 hv = *(const float4*)(hs + j * 4);
      acc0 = fmaf(wreg[4 * j + 0], hv.x, acc0);
      acc1 = fmaf(wreg[4 * j + 1], hv.y, acc1);
      acc2 = fmaf(wreg[4 * j + 2], hv.z, acc2);
      acc3 = fmaf(wreg[4 * j + 3], hv.w, acc3);
    }
    float accv = (acc0 + acc1) + (acc2 + acc3);
    // butterfly over the 16 k-segments (lane bits 2..5)
    accv += __shfl_xor(accv, 4);
    accv += __shfl_xor(accv, 8);
    accv += __shfl_xor(accv, 16);
    accv += __shfl_xor(accv, 32);
    float pre = accv + gxv;
    float act = (g == 2) ? tanhf_(pre) : sigmoidf_(pre);
    // gather the 4 gates (valid combination in g==0 lanes)
    float b1v = __shfl_xor(act, 1);
    float b2v = __shfl_xor(act, 2);
    float b3v = __shfl_xor(act, 3);
    // for g==0: i=act, f=b1v, gg=b2v, o=b3v
    c = fmaf(b1v, c, act * b2v);
    float hn = b3v * tanhf_(c);
    if (lane == 0) {
      __hip_atomic_store(&h_u[(size_t)(t + 1) * H + unit], __float_as_uint(hn),
                         __ATOMIC_RELAXED, __HIP_MEMORY_SCOPE_AGENT);
      if (t == T_SEQ - 1) {
        out[16384 + unit] = hn;  // hT
        out[17408 + unit] = c;   // cT
      }
    }
  }
}

// ---------------- head: action_mean + log_std broadcast ----------------
__global__ __launch_bounds__(256) void head_k(
    const float* __restrict__ h2, const float* __restrict__ mean_w,
    const float* __restrict__ mean_b, const float* __restrict__ log_std,
    float* __restrict__ out) {
  const int t = blockIdx.x;
  const int tid = threadIdx.x;
  const int wave = tid >> 6, lane = tid & 63;  // wave = output index (OUT=4)
  const float* hr = h2 + (size_t)t * H;
  const float* wr = mean_w + (size_t)wave * H;
  float s = 0.f;
#pragma unroll
  for (int j = 0; j < 16; j++) s = fmaf(hr[lane + j * 64], wr[lane + j * 64], s);
#pragma unroll
  for (int off = 32; off > 0; off >>= 1) s += __shfl_down(s, off);
  if (lane == 0) out[t * 4 + wave] = s + mean_b[wave];
  if (tid < 4) out[8192 + t * 4 + tid] = log_std[tid];
}

extern "C" void kernel_launch(void* const* d_in, const int* in_sizes, int n_in,
                              void* d_out, int out_size, void* d_ws, size_t ws_size,
                              hipStream_t stream) {
  const float* x      = (const float*)d_in[0];
  const float* h0     = (const float*)d_in[1];
  const float* c0     = (const float*)d_in[2];
  const float* w_ih   = (const float*)d_in[3];
  const float* w_hh   = (const float*)d_in[4];
  const float* b_ih   = (const float*)d_in[5];
  const float* b_hh   = (const float*)d_in[6];
  const float* fc1_w  = (const float*)d_in[7];
  const float* fc1_b  = (const float*)d_in[8];
  const float* fc2_w  = (const float*)d_in[9];
  const float* fc2_b  = (const float*)d_in[10];
  const float* mean_w = (const float*)d_in[11];
  const float* mean_b = (const float*)d_in[12];
  const float* lstd   = (const float*)d_in[13];
  float* out = (float*)d_out;

  // workspace layout (peak ~40.4 MB):
  //   gx:     [0, 32 MB)              2048*4096 fp32  (reused as h1/h2 after LSTM)
  //   h_hist: [32 MB, 40.4 MB)        2049*1024 fp32  (row 0 = h0, rows 1..2048 = ys)
  float* gx = (float*)d_ws;
  float* h_hist = gx + (size_t)T_SEQ * G4;
  float* h1 = gx;
  float* h2 = gx + (size_t)T_SEQ * H;

  init_k<<<dim3((T_SEQ + 1) * H / 256), 256, 0, stream>>>(h0, h_hist);
  gemm_bias_k<false, true><<<dim3(G4 / BN, T_SEQ / BM), 256, 0, stream>>>(
      x, w_ih, b_ih, b_hh, gx, T_SEQ, G4, K_IN);
  lstm_k<<<dim3(NWG), NTHR, 0, stream>>>(gx, w_hh, c0, h_hist, out);
  gemm_bias_k<true, false><<<dim3(H / BN, T_SEQ / BM), 256, 0, stream>>>(
      h_hist + H, fc1_w, fc1_b, nullptr, h1, T_SEQ, H, H);
  gemm_bias_k<true, false><<<dim3(H / BN, T_SEQ / BM), 256, 0, stream>>>(
      h1, fc2_w, fc2_b, nullptr, h2, T_SEQ, H, H);
  head_k<<<dim3(T_SEQ), 256, 0, stream>>>(h2, mean_w, mean_b, lstd, out);
}

// Round 3
// 3943.831 us; speedup vs baseline: 1.2099x; 1.2099x over previous
//
#include <hip/hip_runtime.h>
#include <stdint.h>

// ActuatorPolicyNet: x[2048,512] -> LSTM(H=1024) -> fc1 -> fc2 -> mean head.
// Phase B: persistent LSTM, 128 wg x 512 thr, unit-per-wave, register-resident
// w_hh (launch_bounds(512,2) -> 256 VGPR budget), 16-B dwordx4 sentinel polls
// by a 256-thread poller subset, single barrier + double-buffered LDS per step.

#define T_SEQ 2048
#define H 1024
#define G4 4096
#define K_IN 512
#define SENT 0x7FC0DEADu  // NaN bit pattern; real h values are never NaN

__device__ __forceinline__ float sigmoidf_(float x) { return 1.0f / (1.0f + __expf(-x)); }
__device__ __forceinline__ float tanhf_(float x) { return 1.0f - 2.0f / (1.0f + __expf(2.0f * x)); }

// 16-B coherent poll load (reads at/near the coherence point: sc0 sc1)
__device__ __forceinline__ uint4 poll_load16(const uint4* p) {
  uint4 v;
  asm volatile("global_load_dwordx4 %0, %1, off sc0 sc1\n\ts_waitcnt vmcnt(0)"
               : "=v"(v) : "v"(p) : "memory");
  return v;
}

// ---------------- init: h_hist[0] = h0, rows 1..2048 = sentinel ----------------
__global__ void init_k(const float* __restrict__ h0, float* __restrict__ h_hist) {
  int idx = blockIdx.x * blockDim.x + threadIdx.x;
  if (idx < H) {
    h_hist[idx] = h0[idx];
  } else if (idx < (T_SEQ + 1) * H) {
    ((unsigned*)h_hist)[idx] = SENT;
  }
}

// ---------------- generic fp32 GEMM: C = act(A[M,K] @ Bw[N,K]^T + b1 (+ b2)) ----------------
#define BM 64
#define BN 64
#define BK 32
#define LDT 68

template <bool RELU, bool HASB2>
__global__ __launch_bounds__(256) void gemm_bias_k(
    const float* __restrict__ A, const float* __restrict__ Bw,
    const float* __restrict__ b1, const float* __restrict__ b2,
    float* __restrict__ C, int M, int N, int K) {
  __shared__ float As[BK][LDT];
  __shared__ float Bs[BK][LDT];
  const int tid = threadIdx.x;
  const int m0 = blockIdx.y * BM;
  const int n0 = blockIdx.x * BN;
  const int tx = tid & 15, ty = tid >> 4;
  const int srow = tid >> 2;
  const int skq = tid & 3;

  float acc[4][4];
#pragma unroll
  for (int i = 0; i < 4; i++)
#pragma unroll
    for (int j = 0; j < 4; j++) acc[i][j] = 0.f;

  const float* Arow = A + (size_t)(m0 + srow) * K;
  const float* Brow = Bw + (size_t)(n0 + srow) * K;

  for (int k0 = 0; k0 < K; k0 += BK) {
    float4 a0 = *(const float4*)(Arow + k0 + skq * 8);
    float4 a1 = *(const float4*)(Arow + k0 + skq * 8 + 4);
    float4 c0_ = *(const float4*)(Brow + k0 + skq * 8);
    float4 c1_ = *(const float4*)(Brow + k0 + skq * 8 + 4);
    __syncthreads();
    const int kb = skq * 8;
    As[kb + 0][srow] = a0.x; As[kb + 1][srow] = a0.y; As[kb + 2][srow] = a0.z; As[kb + 3][srow] = a0.w;
    As[kb + 4][srow] = a1.x; As[kb + 5][srow] = a1.y; As[kb + 6][srow] = a1.z; As[kb + 7][srow] = a1.w;
    Bs[kb + 0][srow] = c0_.x; Bs[kb + 1][srow] = c0_.y; Bs[kb + 2][srow] = c0_.z; Bs[kb + 3][srow] = c0_.w;
    Bs[kb + 4][srow] = c1_.x; Bs[kb + 5][srow] = c1_.y; Bs[kb + 6][srow] = c1_.z; Bs[kb + 7][srow] = c1_.w;
    __syncthreads();
#pragma unroll
    for (int kk = 0; kk < BK; kk++) {
      float av[4], bv[4];
      *(float4*)av = *(const float4*)&As[kk][ty * 4];
      *(float4*)bv = *(const float4*)&Bs[kk][tx * 4];
#pragma unroll
      for (int i = 0; i < 4; i++)
#pragma unroll
        for (int j = 0; j < 4; j++) acc[i][j] = fmaf(av[i], bv[j], acc[i][j]);
    }
  }

  float bb[4];
#pragma unroll
  for (int j = 0; j < 4; j++) {
    bb[j] = b1[n0 + tx * 4 + j];
    if (HASB2) bb[j] += b2[n0 + tx * 4 + j];
  }
#pragma unroll
  for (int i = 0; i < 4; i++) {
    float4 o;
    float* op = (float*)&o;
#pragma unroll
    for (int j = 0; j < 4; j++) {
      float v = acc[i][j] + bb[j];
      op[j] = RELU ? fmaxf(v, 0.f) : v;
    }
    *(float4*)&C[(size_t)(m0 + ty * 4 + i) * N + n0 + tx * 4] = o;
  }
}

// ---------------- persistent LSTM recurrence ----------------
// 128 wgs x 512 thr (8 waves, 2/SIMD). wg owns 8 units; wave owns 1 unit.
// Lane = s*4+g (g=gate i,f,g,o; s=64-wide k-segment). Each lane holds
// w_hh[g*1024+unit][s*64..+64) resident in 64 VGPRs (launch_bounds(512,2)
// gives the 256-VGPR budget that R2's spill proved necessary).
// Exchange: producers store h via agent-scope atomics; 256 pollers/wg each
// spin ONE dwordx4 sc0/sc1 load on a 16-B chunk (data-is-the-flag).
#define NWG 128
#define NTHR 512
#define HPAD 68

__global__ __launch_bounds__(NTHR, 2) void lstm_k(
    const float* __restrict__ gx, const float* __restrict__ w_hh,
    const float* __restrict__ c0, float* __restrict__ h_hist,
    float* __restrict__ out) {
  unsigned* h_u = (unsigned*)h_hist;
  __shared__ float hbuf[2][16 * HPAD];
  const int tid = threadIdx.x;
  const int wg = blockIdx.x;
  const int wave = tid >> 6, lane = tid & 63;
  const int g = lane & 3;        // gate: 0=i 1=f 2=g 3=o
  const int s = lane >> 2;       // k-segment (0..15), 64 values each
  const int unit = wg * 8 + wave;
  const int grow = g * 1024 + unit;

  // preload weights into registers (resident: 64 VGPRs + ~50 overhead < 256)
  float wreg[64];
  {
    const float* wp = w_hh + (size_t)grow * H + s * 64;
#pragma unroll
    for (int j = 0; j < 64; j += 4) {
      float4 w4 = *(const float4*)(wp + j);
      wreg[j] = w4.x; wreg[j + 1] = w4.y; wreg[j + 2] = w4.z; wreg[j + 3] = w4.w;
    }
#pragma unroll
    for (int j = 0; j < 64; j++) asm volatile("" : "+v"(wreg[j]));
  }
  float c = c0[unit];  // meaningful in g==0 lanes only

  const bool poller = tid < 256;
  const int stage_idx = 4 * tid + (tid >> 4) * 4;  // padded LDS slot for poller tid

  for (int t = 0; t < T_SEQ; t++) {
    const int buf = t & 1;
    // prefetch this step's gx so its latency overlaps the poll
    float gxv = gx[(size_t)t * G4 + grow];
    asm volatile("" : "+v"(gxv));

    if (poller) {
      // poll one 16-B chunk of h(t) until all 4 words are non-sentinel
      const uint4* src = (const uint4*)(h_u + (size_t)t * H) + tid;
      uint4 v = poll_load16(src);
      while (v.x == SENT || v.y == SENT || v.z == SENT || v.w == SENT)
        v = poll_load16(src);
      float4 f;
      f.x = __uint_as_float(v.x); f.y = __uint_as_float(v.y);
      f.z = __uint_as_float(v.z); f.w = __uint_as_float(v.w);
      *(float4*)&hbuf[buf][stage_idx] = f;
    }
    __syncthreads();  // single barrier per step (double-buffered hbuf)

    // 64 MACs, 4 accumulators
    float acc0 = 0.f, acc1 = 0.f, acc2 = 0.f, acc3 = 0.f;
    const float* hs = &hbuf[buf][s * HPAD];
#pragma unroll
    for (int j = 0; j < 16; j++) {
      float4 hv = *(const float4*)(hs + j * 4);
      acc0 = fmaf(wreg[4 * j + 0], hv.x, acc0);
      acc1 = fmaf(wreg[4 * j + 1], hv.y, acc1);
      acc2 = fmaf(wreg[4 * j + 2], hv.z, acc2);
      acc3 = fmaf(wreg[4 * j + 3], hv.w, acc3);
    }
    float accv = (acc0 + acc1) + (acc2 + acc3);
    // reduce over the 16 k-segments (lane bits 2..5)
    accv += __shfl_xor(accv, 4);
    accv += __shfl_xor(accv, 8);
    accv += __shfl_xor(accv, 16);
    accv += __shfl_xor(accv, 32);
    float pre = accv + gxv;
    float act = (g == 2) ? tanhf_(pre) : sigmoidf_(pre);
    // gather gates (combination valid in g==0 lanes)
    float b1v = __shfl_xor(act, 1);
    float b2v = __shfl_xor(act, 2);
    float b3v = __shfl_xor(act, 3);
    c = fmaf(b1v, c, act * b2v);        // f*c + i*g   (g==0 lanes)
    float hn = b3v * tanhf_(c);         // o*tanh(c)
    if (lane == 0) {
      __hip_atomic_store(&h_u[(size_t)(t + 1) * H + unit], __float_as_uint(hn),
                         __ATOMIC_RELAXED, __HIP_MEMORY_SCOPE_AGENT);
      if (t == T_SEQ - 1) {
        out[16384 + unit] = hn;  // hT
        out[17408 + unit] = c;   // cT
      }
    }
  }
}

// ---------------- head: action_mean + log_std broadcast ----------------
__global__ __launch_bounds__(256) void head_k(
    const float* __restrict__ h2, const float* __restrict__ mean_w,
    const float* __restrict__ mean_b, const float* __restrict__ log_std,
    float* __restrict__ out) {
  const int t = blockIdx.x;
  const int tid = threadIdx.x;
  const int wave = tid >> 6, lane = tid & 63;  // wave = output index (OUT=4)
  const float* hr = h2 + (size_t)t * H;
  const float* wr = mean_w + (size_t)wave * H;
  float s = 0.f;
#pragma unroll
  for (int j = 0; j < 16; j++) s = fmaf(hr[lane + j * 64], wr[lane + j * 64], s);
#pragma unroll
  for (int off = 32; off > 0; off >>= 1) s += __shfl_down(s, off);
  if (lane == 0) out[t * 4 + wave] = s + mean_b[wave];
  if (tid < 4) out[8192 + t * 4 + tid] = log_std[tid];
}

extern "C" void kernel_launch(void* const* d_in, const int* in_sizes, int n_in,
                              void* d_out, int out_size, void* d_ws, size_t ws_size,
                              hipStream_t stream) {
  const float* x      = (const float*)d_in[0];
  const float* h0     = (const float*)d_in[1];
  const float* c0     = (const float*)d_in[2];
  const float* w_ih   = (const float*)d_in[3];
  const float* w_hh   = (const float*)d_in[4];
  const float* b_ih   = (const float*)d_in[5];
  const float* b_hh   = (const float*)d_in[6];
  const float* fc1_w  = (const float*)d_in[7];
  const float* fc1_b  = (const float*)d_in[8];
  const float* fc2_w  = (const float*)d_in[9];
  const float* fc2_b  = (const float*)d_in[10];
  const float* mean_w = (const float*)d_in[11];
  const float* mean_b = (const float*)d_in[12];
  const float* lstd   = (const float*)d_in[13];
  float* out = (float*)d_out;

  // workspace: gx [0,32MB) (reused as h1/h2), h_hist [32MB, 40.4MB)
  float* gx = (float*)d_ws;
  float* h_hist = gx + (size_t)T_SEQ * G4;
  float* h1 = gx;
  float* h2 = gx + (size_t)T_SEQ * H;

  init_k<<<dim3((T_SEQ + 1) * H / 256), 256, 0, stream>>>(h0, h_hist);
  gemm_bias_k<false, true><<<dim3(G4 / BN, T_SEQ / BM), 256, 0, stream>>>(
      x, w_ih, b_ih, b_hh, gx, T_SEQ, G4, K_IN);
  lstm_k<<<dim3(NWG), NTHR, 0, stream>>>(gx, w_hh, c0, h_hist, out);
  gemm_bias_k<true, false><<<dim3(H / BN, T_SEQ / BM), 256, 0, stream>>>(
      h_hist + H, fc1_w, fc1_b, nullptr, h1, T_SEQ, H, H);
  gemm_bias_k<true, false><<<dim3(H / BN, T_SEQ / BM), 256, 0, stream>>>(
      h1, fc2_w, fc2_b, nullptr, h2, T_SEQ, H, H);
  head_k<<<dim3(T_SEQ), 256, 0, stream>>>(h2, mean_w, mean_b, lstd, out);
}